// Round 3
// baseline (1613.722 us; speedup 1.0000x reference)
//
#include <hip/hip_runtime.h>

// Autoregressive masked net sampler, restructured:
//  - output col i == sampling-time x[:,i]  (masks: out i depends on spins < i only)
//  - spin blocks of KB=8: history part = dense GEMM (MFMA f16, masks all-ones there),
//    intra-block part = sequential per-row (rows independent -> no grid sync)
// R2: seq_block rebuilt thread=(row, single channel): 640 thr/WG (10 waves),
// LDS 59.6 KB -> 2 WG/CU -> 5 waves/SIMD (was 1). Occupancy was the R2 bottleneck
// (OccupancyPercent 10.9, VALUBusy 19).

#define NS   64          // spins
#define HC   20          // hidden channels per spin
#define HTOT 1280        // NS*HC
#define NB   16384       // batch
#define KB   8           // spins per block (8 blocks)
#define BT   32          // batch rows per seq workgroup

typedef _Float16 f16;
typedef _Float16 f16x2 __attribute__((ext_vector_type(2)));
typedef _Float16 f16x8 __attribute__((ext_vector_type(8)));
typedef float f32x4 __attribute__((ext_vector_type(4)));

static __device__ __forceinline__ float dot2f(f16x2 a, f16x2 b, float c) {
#if __has_builtin(__builtin_amdgcn_fdot2)
  return __builtin_amdgcn_fdot2(a, b, c, false);
#else
  return c + (float)a[0] * (float)b[0] + (float)a[1] * (float)b[1];
#endif
}

static __device__ __forceinline__ float dot8f(f16x8 a, f16x8 b, float c) {
  f16x2 a0 = {a[0], a[1]}, a1 = {a[2], a[3]}, a2 = {a[4], a[5]}, a3 = {a[6], a[7]};
  f16x2 b0 = {b[0], b[1]}, b1 = {b[2], b[3]}, b2 = {b[4], b[5]}, b3 = {b[6], b[7]};
  c = dot2f(a0, b0, c);
  c = dot2f(a1, b1, c);
  c = dot2f(a2, b2, c);
  c = dot2f(a3, b3, c);
  return c;
}

static __device__ __forceinline__ float sigm(float z) {
  return __builtin_amdgcn_rcpf(1.0f + __expf(-z));
}

// ---------------------------------------------------------------------------
// prep: build masked, spin-major-permuted f16 weights.
// ---------------------------------------------------------------------------
__global__ __launch_bounds__(256) void prep(
    const float* __restrict__ W1, const float* __restrict__ W2,
    const float* __restrict__ W3, const float* __restrict__ W4,
    const float* __restrict__ W5, const float* __restrict__ W6,
    f16* __restrict__ Wp, f16* __restrict__ W1p, f16* __restrict__ W6p) {
  __shared__ float row[HTOT];
  int bid = blockIdx.x;
  if (bid < 4 * HTOT) {
    int L = bid / HTOT, cp = bid % HTOT;
    int j_o = cp / HC, ch_o = cp % HC;
    const float* Wsrc = (L == 0) ? W2 : (L == 1) ? W3 : (L == 2) ? W4 : W5;
    const float* src = Wsrc + (size_t)(ch_o * NS + j_o) * HTOT;
    for (int k = threadIdx.x; k < HTOT; k += 256) row[k] = src[k];
    __syncthreads();
    f16* dst = Wp + (size_t)bid * HTOT;
    for (int xp = threadIdx.x; xp < HTOT; xp += 256) {
      int j_i = xp / HC, ch_i = xp % HC;
      float v = (j_i <= j_o) ? row[ch_i * NS + j_i] : 0.0f;
      dst[xp] = (f16)v;
    }
  } else if (bid < 4 * HTOT + 320) {
    int rr = (bid - 4 * HTOT) * 4 + (threadIdx.x >> 6);
    int c = threadIdx.x & 63;
    int j_o = rr / HC, ch_o = rr % HC;
    float v = (c < j_o) ? W1[(size_t)(ch_o * NS + j_o) * NS + c] : 0.0f;
    W1p[(size_t)rr * NS + c] = (f16)v;
  } else {
    int i = bid - (4 * HTOT + 320);
    const float* src = W6 + (size_t)i * HTOT;
    for (int k = threadIdx.x; k < HTOT; k += 256) row[k] = src[k];
    __syncthreads();
    for (int xp = threadIdx.x; xp < HTOT; xp += 256) {
      int j_i = xp / HC, ch_i = xp % HC;
      float v = (j_i <= i) ? row[ch_i * NS + j_i] : 0.0f;
      W6p[(size_t)i * HTOT + xp] = (f16)v;
    }
  }
}

// ---------------------------------------------------------------------------
// gemm_block_mfma: history part for layers 2..5 of block starting at spin I.
//   Zg[L][c][b] = sum_{k < 20I} Wp[L][20I + c][k] * AH[L][k][b],  c = 0..159
// MFMA f32_16x16x32_f16; AH [L][g=k/8][b][e=k%8] is the raw B-fragment layout.
// ---------------------------------------------------------------------------
__global__ __launch_bounds__(256) void gemm_block_mfma(
    const f16* __restrict__ Wp, const f16* __restrict__ AH,
    float* __restrict__ Zg, int I, int BS) {
  const int L = blockIdx.y;
  const int w = threadIdx.x >> 6;
  const int wm = w & 1, wn = w >> 1;
  const int l15 = threadIdx.x & 15;
  const int quad = (threadIdx.x & 63) >> 4;
  const int b0 = blockIdx.x * 64 + wn * 32;
  const int G32 = (HC * I) >> 5;

  f32x4 acc[5][2];
#pragma unroll
  for (int mt = 0; mt < 5; ++mt) {
    acc[mt][0] = (f32x4){0.f, 0.f, 0.f, 0.f};
    acc[mt][1] = (f32x4){0.f, 0.f, 0.f, 0.f};
  }

  const f16* aptr = Wp + (size_t)(L * HTOT + HC * I + wm * 80 + l15) * HTOT + quad * 8;
  const f16* bptr = AH + ((size_t)(L * 160 + quad) * BS + b0 + l15) * 8;

  for (int ks = 0; ks < G32; ++ks) {
    f16x8 bf0 = *(const f16x8*)(bptr);
    f16x8 bf1 = *(const f16x8*)(bptr + 128);
    f16x8 af[5];
#pragma unroll
    for (int mt = 0; mt < 5; ++mt)
      af[mt] = *(const f16x8*)(aptr + (size_t)(mt * 16) * HTOT);
#pragma unroll
    for (int mt = 0; mt < 5; ++mt) {
      acc[mt][0] = __builtin_amdgcn_mfma_f32_16x16x32_f16(af[mt], bf0, acc[mt][0], 0, 0, 0);
      acc[mt][1] = __builtin_amdgcn_mfma_f32_16x16x32_f16(af[mt], bf1, acc[mt][1], 0, 0, 0);
    }
    aptr += 32;
    bptr += (size_t)4 * BS * 8;
  }

#pragma unroll
  for (int mt = 0; mt < 5; ++mt)
#pragma unroll
    for (int nt = 0; nt < 2; ++nt)
#pragma unroll
      for (int r = 0; r < 4; ++r) {
        int c = wm * 80 + mt * 16 + quad * 4 + r;
        int b = b0 + nt * 16 + l15;
        Zg[(size_t)(L * 160 + c) * BS + b] = acc[mt][nt][r];
      }
}

// ---------------------------------------------------------------------------
// seq_block v2: 640 threads = 32 rows x 20 channels (10 waves), 2 WG/CU.
// thread (r = tid&31, ch = tid>>5) computes ONE hidden channel per layer step.
// LDS reads broadcast across ch (same address); weight loads broadcast across
// rows (2 distinct addrs per wave -> L1 lines). z6 reduced shfl(32) + 10-slot LDS.
// ---------------------------------------------------------------------------
__global__ __launch_bounds__(640, 5) void seq_block(
    const f16* __restrict__ Wp, const f16* __restrict__ W1p,
    const f16* __restrict__ W6p, f16* __restrict__ AH,
    const float* __restrict__ Zg, f16* __restrict__ s_ws,
    const float* __restrict__ u, float* __restrict__ outp,
    int I, int BS, int b0) {
  __shared__ __align__(16) f16 aL[5][BT][168];   // 53760 B
  __shared__ __align__(16) f16 sL[BT][72];       // 4608 B
  __shared__ float z6p[10][BT];                  // 1280 B   -> total 59648 B

  const int r = threadIdx.x & 31;
  const int ch = threadIdx.x >> 5;      // 0..19
  const int lane = threadIdx.x & 63;
  const int wv = threadIdx.x >> 6;      // 0..9
  const int brel = blockIdx.x * BT + r;
  const int bg = b0 + brel;

  // zero LDS activations / s (masked-weight tails must read as 0)
  {
    f16x8 z = {};
    f16x8* pa = (f16x8*)&aL[0][0][0];
    for (int k = threadIdx.x; k < (5 * BT * 168) / 8; k += 640) pa[k] = z;
    f16x8* ps = (f16x8*)&sL[0][0];
    for (int k = threadIdx.x; k < (BT * 72) / 8; k += 640) ps[k] = z;
  }
  __syncthreads();

  // load sampled-bit history j < I  (I>>3 <= 7 chunks -> ch 0..6 load one each)
  if (ch < (I >> 3)) {
    f16x8 v = *(const f16x8*)(s_ws + (size_t)brel * NS + ch * 8);
    *(f16x8*)&sL[r][ch * 8] = v;
  }

  // layer-6 history partials: z6r[t] += sum over this thread's g-chunks
  float z6r[KB];
#pragma unroll
  for (int t = 0; t < KB; ++t) z6r[t] = 0.0f;
  {
    const int G = (HC * I) >> 3;
    const f16* ah5 = AH + ((size_t)(4 * 160) * BS + brel) * 8;
    for (int g = ch; g < G; g += HC) {
      f16x8 a = *(const f16x8*)(ah5 + (size_t)g * (size_t)BS * 8);
#pragma unroll
      for (int t = 0; t < KB; ++t) {
        f16x8 w = *(const f16x8*)(W6p + (size_t)(I + t) * HTOT + g * 8);
        z6r[t] = dot8f(a, w, z6r[t]);
      }
    }
  }
  __syncthreads();

  for (int t = 0; t < KB; ++t) {
    const int i = I + t;

    // ---- layer 1: gather over sampled bits ----
    {
      float acc = 0.0f;
      const int C1 = (i + 7) >> 3;
      const f16* w1r = W1p + (size_t)(i * HC + ch) * NS;
      for (int c8 = 0; c8 < C1; ++c8) {
        f16x8 sv = *(const f16x8*)&sL[r][c8 * 8];
        f16x8 w = *(const f16x8*)(w1r + c8 * 8);
        acc = dot8f(sv, w, acc);
      }
      aL[0][r][t * HC + ch] = (f16)sigm(acc);
    }
    __syncthreads();

    // ---- layers 2..5: Zg(history GEMM) + intra-block gather ----
    const int C2 = (HC * (t + 1) + 7) >> 3;
    float a5 = 0.0f;
#pragma unroll
    for (int L = 0; L < 4; ++L) {
      float z = Zg[(size_t)(L * 160 + t * HC + ch) * BS + brel];
      const f16* wr = Wp + ((size_t)(L * HTOT + i * HC + ch)) * HTOT + HC * I;
      for (int c8 = 0; c8 < C2; ++c8) {
        f16x8 av = *(const f16x8*)&aL[L][r][c8 * 8];
        f16x8 w = *(const f16x8*)(wr + c8 * 8);
        z = dot8f(av, w, z);
      }
      float a = sigm(z);
      aL[L + 1][r][t * HC + ch] = (f16)a;
      if (L == 3) a5 = a;
      __syncthreads();
    }

    // ---- scatter own a5 channel into z6 partials for t' >= t ----
    for (int tp = t; tp < KB; ++tp)
      z6r[tp] += (float)W6p[(size_t)(I + tp) * HTOT + i * HC + ch] * a5;

    // ---- reduce z6 over 20 channels: shfl pair + 10-slot LDS ----
    {
      float v = z6r[t];
      v += __shfl_down(v, 32, 64);
      if (lane < 32) z6p[wv][r] = v;  // lane == r here
    }
    __syncthreads();
    if (ch == 0) {
      float z6 = 0.0f;
#pragma unroll
      for (int w = 0; w < 10; ++w) z6 += z6p[w][r];
      float x = sigm(z6);
      outp[(size_t)bg * NS + i] = x;  // final output col i == sampling-time x
      float uu = u[(size_t)i * NB + bg];
      sL[r][i] = (f16)((x >= uu) ? 1.0f : -1.0f);
    }
    __syncthreads();
  }

  // ---- bulk writeout: block activations -> global AH ([L][g][b][e]), s bits ----
  for (int w = threadIdx.x; w < 5 * 20 * BT; w += 640) {
    int rr = w & (BT - 1);
    int q = w >> 5;
    int L = q / 20, x8 = q % 20;
    f16x8 v = *(const f16x8*)&aL[L][rr][x8 * 8];
    int gg = ((HC * I) >> 3) + x8;
    *(f16x8*)(AH + ((size_t)(L * 160 + gg) * BS + blockIdx.x * BT + rr) * 8) = v;
  }
  if (threadIdx.x < BT) {
    *(f16x8*)(s_ws + (size_t)(blockIdx.x * BT + threadIdx.x) * NS + I) =
        *(const f16x8*)&sL[threadIdx.x][I];
  }
}

// ---------------------------------------------------------------------------
extern "C" void kernel_launch(void* const* d_in, const int* in_sizes, int n_in,
                              void* d_out, int out_size, void* d_ws, size_t ws_size,
                              hipStream_t stream) {
  (void)in_sizes; (void)n_in; (void)out_size;
  const float* u  = (const float*)d_in[1];
  const float* W1 = (const float*)d_in[2];
  const float* W2 = (const float*)d_in[3];
  const float* W3 = (const float*)d_in[4];
  const float* W4 = (const float*)d_in[5];
  const float* W5 = (const float*)d_in[6];
  const float* W6 = (const float*)d_in[7];
  float* outp = (float*)d_out;

  const size_t wpEls  = (size_t)4 * HTOT * HTOT;
  const size_t w1Els  = (size_t)HTOT * NS;
  const size_t w6Els  = (size_t)NS * HTOT;
  const size_t wBytes = (wpEls + w1Els + w6Els) * sizeof(f16);
  size_t rem = (ws_size > wBytes + 4096) ? (ws_size - wBytes - 4096) : 0;
  long long bs = (long long)(rem / 15488);
  bs = (bs / 64) * 64;
  if (bs > NB) bs = NB;
  if (bs < 64) bs = 64;
  const int BS = (int)bs;

  f16* Wp  = (f16*)d_ws;
  f16* W1p = Wp + wpEls;
  f16* W6p = W1p + w1Els;
  f16* AH  = W6p + w6Els;
  float* Zg = (float*)(AH + (size_t)5 * 160 * BS * 8);
  f16* s_ws = (f16*)(Zg + (size_t)4 * 160 * BS);

  prep<<<dim3(4 * HTOT + 320 + NS), dim3(256), 0, stream>>>(
      W1, W2, W3, W4, W5, W6, Wp, W1p, W6p);

  for (int c0 = 0; c0 < NB; c0 += BS) {
    int nr = NB - c0; if (nr > BS) nr = BS;
    for (int m = 0; m < NS / KB; ++m) {
      const int I = m * KB;
      gemm_block_mfma<<<dim3(nr / 64, 4), dim3(256), 0, stream>>>(Wp, AH, Zg, I, BS);
      seq_block<<<dim3(nr / BT), dim3(640), 0, stream>>>(
          Wp, W1p, W6p, AH, Zg, s_ws, u, outp, I, BS, c0);
    }
  }
}

// Round 4
// 1327.264 us; speedup vs baseline: 1.2158x; 1.2158x over previous
//
#include <hip/hip_runtime.h>

// Autoregressive masked net sampler, restructured:
//  - output col i == sampling-time x[:,i]  (masks: out i depends on spins < i only)
//  - spin blocks of KB=8: history part = dense GEMM (MFMA f16, masks all-ones there),
//    intra-block part = sequential per-row (rows independent -> no grid sync)
// R3 lesson: 1 ch/thread (640 thr) raised occupancy but 5x'd LDS traffic and killed
// ILP -> slower. R4: single-wave WGs (BT=16 rows x 4 quads = 64 thr): __syncthreads
// degenerates to waitcnt (no barrier), LDS 29.2 KB -> 5 WG/CU, 5 ch/thread ILP kept.

#define NS   64          // spins
#define HC   20          // hidden channels per spin
#define HTOT 1280        // NS*HC
#define NB   16384       // batch
#define KB   8           // spins per block (8 blocks)
#define BT   16          // batch rows per seq workgroup (single wave: 16 x 4)

typedef _Float16 f16;
typedef _Float16 f16x2 __attribute__((ext_vector_type(2)));
typedef _Float16 f16x8 __attribute__((ext_vector_type(8)));
typedef float f32x4 __attribute__((ext_vector_type(4)));

static __device__ __forceinline__ float dot2f(f16x2 a, f16x2 b, float c) {
#if __has_builtin(__builtin_amdgcn_fdot2)
  return __builtin_amdgcn_fdot2(a, b, c, false);
#else
  return c + (float)a[0] * (float)b[0] + (float)a[1] * (float)b[1];
#endif
}

static __device__ __forceinline__ float dot8f(f16x8 a, f16x8 b, float c) {
  f16x2 a0 = {a[0], a[1]}, a1 = {a[2], a[3]}, a2 = {a[4], a[5]}, a3 = {a[6], a[7]};
  f16x2 b0 = {b[0], b[1]}, b1 = {b[2], b[3]}, b2 = {b[4], b[5]}, b3 = {b[6], b[7]};
  c = dot2f(a0, b0, c);
  c = dot2f(a1, b1, c);
  c = dot2f(a2, b2, c);
  c = dot2f(a3, b3, c);
  return c;
}

static __device__ __forceinline__ float sigm(float z) {
  return __builtin_amdgcn_rcpf(1.0f + __expf(-z));
}

// ---------------------------------------------------------------------------
// prep: build masked, spin-major-permuted f16 weights.
//  Wp [L=0..3][cp][xp]  cp = j_out*20+ch_out, xp = j_in*20+ch_in, mask j_in <= j_out
//  W1p[cp][j_in]        mask j_in <  j_out  (exclusive)
//  W6p[i][xp]           mask j_in <= i
// ---------------------------------------------------------------------------
__global__ __launch_bounds__(256) void prep(
    const float* __restrict__ W1, const float* __restrict__ W2,
    const float* __restrict__ W3, const float* __restrict__ W4,
    const float* __restrict__ W5, const float* __restrict__ W6,
    f16* __restrict__ Wp, f16* __restrict__ W1p, f16* __restrict__ W6p) {
  __shared__ float row[HTOT];
  int bid = blockIdx.x;
  if (bid < 4 * HTOT) {
    int L = bid / HTOT, cp = bid % HTOT;
    int j_o = cp / HC, ch_o = cp % HC;
    const float* Wsrc = (L == 0) ? W2 : (L == 1) ? W3 : (L == 2) ? W4 : W5;
    const float* src = Wsrc + (size_t)(ch_o * NS + j_o) * HTOT;
    for (int k = threadIdx.x; k < HTOT; k += 256) row[k] = src[k];
    __syncthreads();
    f16* dst = Wp + (size_t)bid * HTOT;
    for (int xp = threadIdx.x; xp < HTOT; xp += 256) {
      int j_i = xp / HC, ch_i = xp % HC;
      float v = (j_i <= j_o) ? row[ch_i * NS + j_i] : 0.0f;
      dst[xp] = (f16)v;
    }
  } else if (bid < 4 * HTOT + 320) {
    int rr = (bid - 4 * HTOT) * 4 + (threadIdx.x >> 6);
    int c = threadIdx.x & 63;
    int j_o = rr / HC, ch_o = rr % HC;
    float v = (c < j_o) ? W1[(size_t)(ch_o * NS + j_o) * NS + c] : 0.0f;
    W1p[(size_t)rr * NS + c] = (f16)v;
  } else {
    int i = bid - (4 * HTOT + 320);
    const float* src = W6 + (size_t)i * HTOT;
    for (int k = threadIdx.x; k < HTOT; k += 256) row[k] = src[k];
    __syncthreads();
    for (int xp = threadIdx.x; xp < HTOT; xp += 256) {
      int j_i = xp / HC, ch_i = xp % HC;
      float v = (j_i <= i) ? row[ch_i * NS + j_i] : 0.0f;
      W6p[(size_t)i * HTOT + xp] = (f16)v;
    }
  }
}

// ---------------------------------------------------------------------------
// gemm_block_mfma: history part for layers 2..5 of block starting at spin I.
//   Zg[L][c][b] = sum_{k < 20I} Wp[L][20I + c][k] * AH[L][k][b],  c = 0..159
// MFMA f32_16x16x32_f16; AH [L][g=k/8][b][e=k%8] is the raw B-fragment layout.
// ---------------------------------------------------------------------------
__global__ __launch_bounds__(256) void gemm_block_mfma(
    const f16* __restrict__ Wp, const f16* __restrict__ AH,
    float* __restrict__ Zg, int I, int BS) {
  const int L = blockIdx.y;
  const int w = threadIdx.x >> 6;
  const int wm = w & 1, wn = w >> 1;
  const int l15 = threadIdx.x & 15;
  const int quad = (threadIdx.x & 63) >> 4;
  const int b0 = blockIdx.x * 64 + wn * 32;
  const int G32 = (HC * I) >> 5;

  f32x4 acc[5][2];
#pragma unroll
  for (int mt = 0; mt < 5; ++mt) {
    acc[mt][0] = (f32x4){0.f, 0.f, 0.f, 0.f};
    acc[mt][1] = (f32x4){0.f, 0.f, 0.f, 0.f};
  }

  const f16* aptr = Wp + (size_t)(L * HTOT + HC * I + wm * 80 + l15) * HTOT + quad * 8;
  const f16* bptr = AH + ((size_t)(L * 160 + quad) * BS + b0 + l15) * 8;

  for (int ks = 0; ks < G32; ++ks) {
    f16x8 bf0 = *(const f16x8*)(bptr);
    f16x8 bf1 = *(const f16x8*)(bptr + 128);
    f16x8 af[5];
#pragma unroll
    for (int mt = 0; mt < 5; ++mt)
      af[mt] = *(const f16x8*)(aptr + (size_t)(mt * 16) * HTOT);
#pragma unroll
    for (int mt = 0; mt < 5; ++mt) {
      acc[mt][0] = __builtin_amdgcn_mfma_f32_16x16x32_f16(af[mt], bf0, acc[mt][0], 0, 0, 0);
      acc[mt][1] = __builtin_amdgcn_mfma_f32_16x16x32_f16(af[mt], bf1, acc[mt][1], 0, 0, 0);
    }
    aptr += 32;
    bptr += (size_t)4 * BS * 8;
  }

#pragma unroll
  for (int mt = 0; mt < 5; ++mt)
#pragma unroll
    for (int nt = 0; nt < 2; ++nt)
#pragma unroll
      for (int r = 0; r < 4; ++r) {
        int c = wm * 80 + mt * 16 + quad * 4 + r;
        int b = b0 + nt * 16 + l15;
        Zg[(size_t)(L * 160 + c) * BS + b] = acc[mt][nt][r];
      }
}

// ---------------------------------------------------------------------------
// seq_block v3 (single-wave WG): 64 threads = 16 rows x 4 channel-quads (5 ch each).
// __syncthreads in a 1-wave WG is just a waitcnt -> no barrier stalls. 5 ch/thread
// keeps 5 independent dot chains (ILP). LDS 29.2 KB -> 5 WG/CU. z6 cross-quad
// reduction via shfl_xor(16/32), no LDS.
// ---------------------------------------------------------------------------
__global__ __launch_bounds__(64) void seq_block(
    const f16* __restrict__ Wp, const f16* __restrict__ W1p,
    const f16* __restrict__ W6p, f16* __restrict__ AH,
    const float* __restrict__ Zg, f16* __restrict__ s_ws,
    const float* __restrict__ u, float* __restrict__ outp,
    int I, int BS, int b0) {
  __shared__ __align__(16) f16 aL[5][BT][168];   // 26880 B
  __shared__ __align__(16) f16 sL[BT][72];       // 2304 B  -> 29184 B total

  const int lane = threadIdx.x;
  const int r = lane & 15;
  const int cq = lane >> 4;             // 0..3, channels 5*cq..5*cq+4
  const int brel = blockIdx.x * BT + r;
  const int bg = b0 + brel;

  // zero LDS activations / s (masked-weight tails must read as 0)
  {
    f16x8 z = {};
    f16x8* pa = (f16x8*)&aL[0][0][0];
    for (int k = lane; k < (5 * BT * 168) / 8; k += 64) pa[k] = z;
    f16x8* ps = (f16x8*)&sL[0][0];
    for (int k = lane; k < (BT * 72) / 8; k += 64) ps[k] = z;
  }
  __syncthreads();

  // load sampled-bit history j < I
  for (int c8 = cq; c8 < (I >> 3); c8 += 4) {
    f16x8 v = *(const f16x8*)(s_ws + (size_t)brel * NS + c8 * 8);
    *(f16x8*)&sL[r][c8 * 8] = v;
  }

  // layer-6 history partials (this thread's g-subset; reduced at output via shfl)
  float z6r[KB];
#pragma unroll
  for (int t = 0; t < KB; ++t) z6r[t] = 0.0f;
  {
    const int G = (HC * I) >> 3;
    const f16* ah5 = AH + ((size_t)(4 * 160) * BS + brel) * 8;
    for (int g = cq; g < G; g += 4) {
      f16x8 a = *(const f16x8*)(ah5 + (size_t)g * (size_t)BS * 8);
#pragma unroll
      for (int t = 0; t < KB; ++t) {
        f16x8 w = *(const f16x8*)(W6p + (size_t)(I + t) * HTOT + g * 8);
        z6r[t] = dot8f(a, w, z6r[t]);
      }
    }
  }
  __syncthreads();

  for (int t = 0; t < KB; ++t) {
    const int i = I + t;

    // ---- layer 1: gather over sampled bits ----
    {
      float acc[5] = {0, 0, 0, 0, 0};
      const int C1 = (i + 7) >> 3;
      for (int c8 = 0; c8 < C1; ++c8) {
        f16x8 sv = *(const f16x8*)&sL[r][c8 * 8];
#pragma unroll
        for (int k = 0; k < 5; ++k) {
          f16x8 w = *(const f16x8*)(W1p + (size_t)(i * HC + cq * 5 + k) * NS + c8 * 8);
          acc[k] = dot8f(sv, w, acc[k]);
        }
      }
#pragma unroll
      for (int k = 0; k < 5; ++k)
        aL[0][r][t * HC + cq * 5 + k] = (f16)sigm(acc[k]);
    }
    __syncthreads();

    // ---- layers 2..5: Zg(history GEMM) + intra-block gather ----
    const int C2 = (HC * (t + 1) + 7) >> 3;
    float a5r[5];
    for (int L = 0; L < 4; ++L) {
      float z[5];
#pragma unroll
      for (int k = 0; k < 5; ++k)
        z[k] = Zg[(size_t)(L * 160 + t * HC + cq * 5 + k) * BS + brel];
      const f16* wrow = Wp + ((size_t)(L * HTOT + i * HC + cq * 5)) * HTOT + HC * I;
      for (int c8 = 0; c8 < C2; ++c8) {
        f16x8 av = *(const f16x8*)&aL[L][r][c8 * 8];
#pragma unroll
        for (int k = 0; k < 5; ++k) {
          f16x8 w = *(const f16x8*)(wrow + (size_t)k * HTOT + c8 * 8);
          z[k] = dot8f(av, w, z[k]);
        }
      }
#pragma unroll
      for (int k = 0; k < 5; ++k) {
        float a = sigm(z[k]);
        aL[L + 1][r][t * HC + cq * 5 + k] = (f16)a;
        if (L == 3) a5r[k] = a;
      }
      __syncthreads();
    }

    // ---- scatter a5(spin i) into z6 partials for t' >= t ----
    for (int tp = t; tp < KB; ++tp) {
      float zz = z6r[tp];
#pragma unroll
      for (int k = 0; k < 5; ++k)
        zz += (float)W6p[(size_t)(I + tp) * HTOT + i * HC + cq * 5 + k] * a5r[k];
      z6r[tp] = zz;
    }

    // ---- reduce z6 over 4 quads via shfl_xor; output + sample bit ----
    {
      float v = z6r[t];
      v += __shfl_xor(v, 16, 64);
      v += __shfl_xor(v, 32, 64);
      if (lane < 16) {
        float x = sigm(v);
        outp[(size_t)bg * NS + i] = x;  // final output col i == sampling-time x
        float uu = u[(size_t)i * NB + bg];
        sL[r][i] = (f16)((x >= uu) ? 1.0f : -1.0f);
      }
    }
    __syncthreads();
  }

  // ---- bulk writeout: block activations -> global AH ([L][g][b][e]), s bits ----
  for (int w = lane; w < 5 * 20 * BT; w += 64) {
    int rr = w & (BT - 1);
    int q = w >> 4;            // 0..99
    int L = q / 20, x8 = q % 20;
    f16x8 v = *(const f16x8*)&aL[L][rr][x8 * 8];
    int gg = ((HC * I) >> 3) + x8;
    *(f16x8*)(AH + ((size_t)(L * 160 + gg) * BS + blockIdx.x * BT + rr) * 8) = v;
  }
  if (lane < BT) {
    *(f16x8*)(s_ws + (size_t)(blockIdx.x * BT + lane) * NS + I) =
        *(const f16x8*)&sL[lane][I];
  }
}

// ---------------------------------------------------------------------------
extern "C" void kernel_launch(void* const* d_in, const int* in_sizes, int n_in,
                              void* d_out, int out_size, void* d_ws, size_t ws_size,
                              hipStream_t stream) {
  (void)in_sizes; (void)n_in; (void)out_size;
  const float* u  = (const float*)d_in[1];
  const float* W1 = (const float*)d_in[2];
  const float* W2 = (const float*)d_in[3];
  const float* W3 = (const float*)d_in[4];
  const float* W4 = (const float*)d_in[5];
  const float* W5 = (const float*)d_in[6];
  const float* W6 = (const float*)d_in[7];
  float* outp = (float*)d_out;

  const size_t wpEls  = (size_t)4 * HTOT * HTOT;
  const size_t w1Els  = (size_t)HTOT * NS;
  const size_t w6Els  = (size_t)NS * HTOT;
  const size_t wBytes = (wpEls + w1Els + w6Els) * sizeof(f16);
  size_t rem = (ws_size > wBytes + 4096) ? (ws_size - wBytes - 4096) : 0;
  long long bs = (long long)(rem / 15488);
  bs = (bs / 64) * 64;
  if (bs > NB) bs = NB;
  if (bs < 64) bs = 64;
  const int BS = (int)bs;

  f16* Wp  = (f16*)d_ws;
  f16* W1p = Wp + wpEls;
  f16* W6p = W1p + w1Els;
  f16* AH  = W6p + w6Els;
  float* Zg = (float*)(AH + (size_t)5 * 160 * BS * 8);
  f16* s_ws = (f16*)(Zg + (size_t)4 * 160 * BS);

  prep<<<dim3(4 * HTOT + 320 + NS), dim3(256), 0, stream>>>(
      W1, W2, W3, W4, W5, W6, Wp, W1p, W6p);

  for (int c0 = 0; c0 < NB; c0 += BS) {
    int nr = NB - c0; if (nr > BS) nr = BS;
    for (int m = 0; m < NS / KB; ++m) {
      const int I = m * KB;
      gemm_block_mfma<<<dim3(nr / 64, 4), dim3(256), 0, stream>>>(Wp, AH, Zg, I, BS);
      seq_block<<<dim3(nr / BT), dim3(64), 0, stream>>>(
          Wp, W1p, W6p, AH, Zg, s_ws, u, outp, I, BS, c0);
    }
  }
}